// Round 8
// baseline (224.604 us; speedup 1.0000x reference)
//
#include <hip/hip_runtime.h>
#include <hip/hip_bf16.h>
#include <math.h>

typedef __bf16 bf16x8 __attribute__((ext_vector_type(8)));
typedef __bf16 bf16x4 __attribute__((ext_vector_type(4)));
typedef float f32x4 __attribute__((ext_vector_type(4)));

#define TM 128
#define BK 64   // bf16 elements per K-tile (8 chunks of 16B per row)

__device__ inline void async16(const void* g, void* l) {
    __builtin_amdgcn_global_load_lds(
        (const __attribute__((address_space(1))) unsigned int*)g,
        (__attribute__((address_space(3))) unsigned int*)l, 16, 0, 0);
}

// Stage a R x 64 bf16 tile with XOR chunk swizzle: LDS chunk (r,c) holds global
// chunk (r, c^(r&7)). Readers then hit all 32 banks (2-way = free; R6: 0 conflicts).
__device__ inline void stage_sw(__bf16* S, const __bf16* G, int row0, int K, int k0,
                                int tid, int nchunks) {
#pragma unroll
    for (int ci = tid; ci < nchunks; ci += 256) {
        const int r  = ci >> 3;
        const int c  = ci & 7;
        const int cg = c ^ (r & 7);
        const char* g = (const char*)G + ((size_t)(row0 + r) * K + k0 + cg * 8) * 2;
        async16(g, (char*)S + ci * 16);
    }
}

// Swizzled fragment read: global chunk (r, cfrag) lives at LDS chunk cfrag^(r&7).
__device__ inline bf16x8 frag_sw(const __bf16* S, int r, int cfrag) {
    const int c = cfrag ^ (r & 7);
    return *(const bf16x8*)(S + r * 64 + c * 8);
}

// Direct global fragment load (coalesced 16B/lane).
__device__ inline bf16x8 frag_g(const __bf16* G, int row, int K, int kcol) {
    return *(const bf16x8*)(G + (size_t)row * K + kcol);
}

// fp32 -> bf16 hi (+ optional lo). blockIdx.y selects {x, w_qkv, w_out}.
__global__ __launch_bounds__(256) void split_mat(
    const float* __restrict__ s0, __bf16* __restrict__ h0, __bf16* __restrict__ l0, int n0,
    const float* __restrict__ s1, __bf16* __restrict__ h1, __bf16* __restrict__ l1, int n1,
    const float* __restrict__ s2, __bf16* __restrict__ h2, __bf16* __restrict__ l2, int n2)
{
    const float* s; __bf16* h; __bf16* l; int n;
    if (blockIdx.y == 0)      { s = s0; h = h0; l = l0; n = n0; }
    else if (blockIdx.y == 1) { s = s1; h = h1; l = l1; n = n1; }
    else                      { s = s2; h = h2; l = l2; n = n2; }
    const int base = (blockIdx.x * 256 + threadIdx.x) * 8;
    if (base >= n) return;
    float4 a = ((const float4*)(s + base))[0];
    float4 b = ((const float4*)(s + base))[1];
    float buf[8] = {a.x, a.y, a.z, a.w, b.x, b.y, b.z, b.w};
    bf16x8 hv, lv;
#pragma unroll
    for (int j = 0; j < 8; j++) {
        __bf16 hb = (__bf16)buf[j];
        hv[j] = hb;
        lv[j] = (__bf16)(buf[j] - (float)hb);
    }
    *(bf16x8*)(h + base) = hv;
    if (l) *(bf16x8*)(l + base) = lv;
}

// QKV projection: C = A*W^T + bias (plain bf16 1-term MFMA).
// A fragments loaded DIRECT from global (L2-hot); W staged in LDS (swizzled).
// Fused QK-norm, scatter q/k/v bf16 into [B,H,N,64]. TN=128.
__global__ __launch_bounds__(256) void gemm_qkv(
    const __bf16* __restrict__ A, const __bf16* __restrict__ W,
    const float* __restrict__ bias,
    __bf16* __restrict__ q, __bf16* __restrict__ k, __bf16* __restrict__ v,
    int M, int N, int K)
{
    __shared__ __bf16 sW[128 * BK];

    const int tid  = threadIdx.x;
    const int lane = tid & 63;
    const int wave = tid >> 6;
    const int bm = blockIdx.y * TM;
    const int bn = blockIdx.x * 128;
    const int wm = (wave >> 1) * 64;
    const int wn = (wave & 1) * 64;
    const int frow = lane & 15;

    f32x4 acc[4][4] = {};

    for (int k0 = 0; k0 < K; k0 += BK) {
        stage_sw(sW, W, bn, K, k0, tid, 128 * 8);
        __syncthreads();

#pragma unroll
        for (int half = 0; half < 2; half++) {
            const int cf = half * 4 + (lane >> 4);
            bf16x8 aF[4], bF[4];
#pragma unroll
            for (int t = 0; t < 4; t++) {
                aF[t] = frag_g(A, bm + wm + t * 16 + frow, K, k0 + cf * 8);
                bF[t] = frag_sw(sW, wn + t * 16 + frow, cf);
            }
#pragma unroll
            for (int i = 0; i < 4; i++)
#pragma unroll
                for (int j = 0; j < 4; j++)
                    acc[i][j] = __builtin_amdgcn_mfma_f32_16x16x32_bf16(aF[i], bF[j], acc[i][j], 0, 0, 0);
        }
        __syncthreads();
    }

    // wave's 64-col window = exactly one (tensor t, head h)
    const int col0 = bn + wn;
    const int t  = col0 >> 10;            // 0=q 1=k 2=v
    const int h  = (col0 & 1023) >> 6;

    float bv[4];
#pragma unroll
    for (int j = 0; j < 4; j++) bv[j] = bias[col0 + j * 16 + (lane & 15)];

    // fused QK-norm: per output row, 1/(||row||+eps)
    float inv_n[4][4];
    if (t < 2) {
#pragma unroll
        for (int i = 0; i < 4; i++)
#pragma unroll
            for (int r = 0; r < 4; r++) {
                float ss = 0.f;
#pragma unroll
                for (int j = 0; j < 4; j++) {
                    float val = acc[i][j][r] + bv[j];
                    ss = fmaf(val, val, ss);
                }
                ss += __shfl_xor(ss, 1);
                ss += __shfl_xor(ss, 2);
                ss += __shfl_xor(ss, 4);
                ss += __shfl_xor(ss, 8);
                inv_n[i][r] = 1.0f / (sqrtf(ss) + 1e-6f);
            }
    }

    __bf16* dstbase = (t == 0) ? q : (t == 1) ? k : v;
#pragma unroll
    for (int i = 0; i < 4; i++) {
        const int gmBase = bm + wm + i * 16 + (lane >> 4) * 4;
#pragma unroll
        for (int j = 0; j < 4; j++) {
            const int dd = (wn & 63) + j * 16 + (lane & 15);
#pragma unroll
            for (int r = 0; r < 4; r++) {
                const int gm = gmBase + r;
                float val = acc[i][j][r] + bv[j];
                if (t < 2) val *= inv_n[i][r];
                const int b  = gm >> 11;
                const int ii = gm & 2047;
                const size_t dst = (((size_t)(b * 16 + h) * 2048) + ii) * 64 + dd;
                dstbase[dst] = (__bf16)val;
            }
        }
    }
}

// Out projection: C = A(Wh+Wl)^T + bias, A bf16 direct-from-global (2-term W), fp32 out.
// TM=128, TN=64 -> 512 blocks (2/CU). Wave owns 64x32.
__global__ __launch_bounds__(256) void gemm_out(
    const __bf16* __restrict__ A,
    const __bf16* __restrict__ Wh, const __bf16* __restrict__ Wl,
    const float* __restrict__ bias, float* __restrict__ C,
    int M, int N, int K)
{
    __shared__ __bf16 sWh[64 * BK];
    __shared__ __bf16 sWl[64 * BK];

    const int tid  = threadIdx.x;
    const int lane = tid & 63;
    const int wave = tid >> 6;
    const int bm = blockIdx.y * TM;
    const int bn = blockIdx.x * 64;
    const int wm = (wave >> 1) * 64;
    const int wn = (wave & 1) * 32;
    const int frow = lane & 15;

    f32x4 acc[4][2] = {};

    for (int k0 = 0; k0 < K; k0 += BK) {
        stage_sw(sWh, Wh, bn, K, k0, tid, 64 * 8);
        stage_sw(sWl, Wl, bn, K, k0, tid, 64 * 8);
        __syncthreads();

#pragma unroll
        for (int half = 0; half < 2; half++) {
            const int cf = half * 4 + (lane >> 4);
            bf16x8 aH[4], bH[2], bL[2];
#pragma unroll
            for (int t = 0; t < 4; t++)
                aH[t] = frag_g(A, bm + wm + t * 16 + frow, K, k0 + cf * 8);
#pragma unroll
            for (int t = 0; t < 2; t++) {
                bH[t] = frag_sw(sWh, wn + t * 16 + frow, cf);
                bL[t] = frag_sw(sWl, wn + t * 16 + frow, cf);
            }
#pragma unroll
            for (int i = 0; i < 4; i++)
#pragma unroll
                for (int j = 0; j < 2; j++) {
                    acc[i][j] = __builtin_amdgcn_mfma_f32_16x16x32_bf16(aH[i], bH[j], acc[i][j], 0, 0, 0);
                    acc[i][j] = __builtin_amdgcn_mfma_f32_16x16x32_bf16(aH[i], bL[j], acc[i][j], 0, 0, 0);
                }
        }
        __syncthreads();
    }

#pragma unroll
    for (int i = 0; i < 4; i++) {
        const int gmBase = bm + wm + i * 16 + (lane >> 4) * 4;
#pragma unroll
        for (int j = 0; j < 2; j++) {
            const int gn = bn + wn + j * 16 + (lane & 15);
            const float bvj = bias[gn];
#pragma unroll
            for (int r = 0; r < 4; r++)
                C[(size_t)(gmBase + r) * N + gn] = acc[i][j][r] + bvj;
        }
    }
}

// Dilated attention: 4 rows per wave; lane group g=lane>>4 owns row i0+g,
// lane&15 owns 4 head-dims (bf16x4). q,k,v: [B,H,N,64] bf16 (q,k normalized).
__global__ __launch_bounds__(256) void attn_sparse(
    const __bf16* __restrict__ q, const __bf16* __restrict__ k,
    const __bf16* __restrict__ v, __bf16* __restrict__ ao /*[B,N,D] bf16*/)
{
    const int wid  = blockIdx.x * 4 + (threadIdx.x >> 6);
    const int lane = threadIdx.x & 63;
    const int g    = lane >> 4;
    const int ld   = (lane & 15) * 4;

    const int bh = wid >> 9;            // 512 wave-tasks per (b,h)
    const int i  = (wid & 511) * 4 + g; // this lane-group's row

    const __bf16* qb = q + (size_t)bh * 2048 * 64;
    const __bf16* kb = k + (size_t)bh * 2048 * 64;
    const __bf16* vb = v + (size_t)bh * 2048 * 64;

    bf16x4 qv = *(const bf16x4*)(qb + (size_t)i * 64 + ld);
    float q0 = (float)qv[0], q1 = (float)qv[1], q2 = (float)qv[2], q3 = (float)qv[3];

    float s[17];
#pragma unroll
    for (int t = 0; t < 17; t++) {
        const int j = i + 2 * t - 16;
        const bool valid = (j >= 0) && (j < 2048);
        const int jc = valid ? j : i;
        bf16x4 kv = *(const bf16x4*)(kb + (size_t)jc * 64 + ld);
        float prod = q0 * (float)kv[0];
        prod = fmaf(q1, (float)kv[1], prod);
        prod = fmaf(q2, (float)kv[2], prod);
        prod = fmaf(q3, (float)kv[3], prod);
        prod += __shfl_xor(prod, 1);
        prod += __shfl_xor(prod, 2);
        prod += __shfl_xor(prod, 4);
        prod += __shfl_xor(prod, 8);
        s[t] = valid ? prod : -INFINITY;
    }

    float m = s[0];
#pragma unroll
    for (int t = 1; t < 17; t++) m = fmaxf(m, s[t]);
    float denom = 0.f, p[17];
#pragma unroll
    for (int t = 0; t < 17; t++) { p[t] = __expf(s[t] - m); denom += p[t]; }
    const float inv = 1.0f / denom;

    float a0 = 0.f, a1 = 0.f, a2 = 0.f, a3 = 0.f;
#pragma unroll
    for (int t = 0; t < 17; t++) {
        const int j = i + 2 * t - 16;
        const int jc = (j >= 0 && j < 2048) ? j : i;   // p[t]==0 when invalid
        bf16x4 vv = *(const bf16x4*)(vb + (size_t)jc * 64 + ld);
        a0 = fmaf(p[t], (float)vv[0], a0);
        a1 = fmaf(p[t], (float)vv[1], a1);
        a2 = fmaf(p[t], (float)vv[2], a2);
        a3 = fmaf(p[t], (float)vv[3], a3);
    }

    const int b = bh >> 4, h = bh & 15;
    bf16x4 o;
    o[0] = (__bf16)(a0 * inv); o[1] = (__bf16)(a1 * inv);
    o[2] = (__bf16)(a2 * inv); o[3] = (__bf16)(a3 * inv);
    *(bf16x4*)(ao + ((size_t)(b * 2048 + i)) * 1024 + h * 64 + ld) = o;
}

extern "C" void kernel_launch(void* const* d_in, const int* in_sizes, int n_in,
                              void* d_out, int out_size, void* d_ws, size_t ws_size,
                              hipStream_t stream)
{
    const float* x     = (const float*)d_in[0];  // [2,2048,1024]
    const float* w_qkv = (const float*)d_in[1];  // [3072,1024]
    const float* b_qkv = (const float*)d_in[2];  // [3072]
    const float* w_out = (const float*)d_in[3];  // [1024,1024]
    const float* b_out = (const float*)d_in[4];  // [1024]
    float* out = (float*)d_out;                  // [2,2048,1024]

    const int Dn = 1024;
    const int M  = 4096;
    const int nx = 4194304, nwq = 3145728, nwo = 1048576;

    char* p = (char*)d_ws;
    __bf16* q   = (__bf16*)p;  p += (size_t)nx * 2;   // [2,16,2048,64]
    __bf16* kk  = (__bf16*)p;  p += (size_t)nx * 2;
    __bf16* vv  = (__bf16*)p;  p += (size_t)nx * 2;
    __bf16* xh  = (__bf16*)p;  p += (size_t)nx * 2;   // aliased to ao after gemm_qkv
    __bf16* wqh = (__bf16*)p;  p += (size_t)nwq * 2;
    __bf16* woh = (__bf16*)p;  p += (size_t)nwo * 2;
    __bf16* wol = (__bf16*)p;  p += (size_t)nwo * 2;
    __bf16* ao  = xh;

    // 0) x, w_qkv -> bf16 cast; w_out -> hi/lo bf16 split
    {
        dim3 grid(nx / 8 / 256, 3);
        hipLaunchKernelGGL(split_mat, grid, dim3(256), 0, stream,
                           x, xh, (__bf16*)nullptr, nx,
                           w_qkv, wqh, (__bf16*)nullptr, nwq,
                           w_out, woh, wol, nwo);
    }
    // 1) qkv projection (1-term, A direct) + fused qk-norm -> q,k,v bf16 head layout
    {
        dim3 grid(3 * Dn / 128, M / TM);
        hipLaunchKernelGGL(gemm_qkv, grid, dim3(256), 0, stream,
                           xh, wqh, b_qkv, q, kk, vv, M, 3 * Dn, Dn);
    }
    // 2) sparse dilated attention -> ao bf16 [B,N,D]
    hipLaunchKernelGGL(attn_sparse, dim3(65536 / 16), dim3(256), 0, stream,
                       q, kk, vv, ao);
    // 3) output projection (2-term W, A direct) -> fp32 out
    {
        dim3 grid(Dn / 64, M / TM);
        hipLaunchKernelGGL(gemm_out, grid, dim3(256), 0, stream,
                           ao, woh, wol, b_out, out, M, Dn, Dn);
    }
}

// Round 9
// 166.623 us; speedup vs baseline: 1.3480x; 1.3480x over previous
//
#include <hip/hip_runtime.h>
#include <hip/hip_bf16.h>
#include <math.h>

typedef __bf16 bf16x8 __attribute__((ext_vector_type(8)));
typedef float f32x4 __attribute__((ext_vector_type(4)));

#define TM 128
#define BK 64   // bf16 elements per K-tile (8 chunks of 16B per row)

__device__ inline void async16(const void* g, void* l) {
    __builtin_amdgcn_global_load_lds(
        (const __attribute__((address_space(1))) unsigned int*)g,
        (__attribute__((address_space(3))) unsigned int*)l, 16, 0, 0);
}

// Stage a R x 64 bf16 tile with XOR chunk swizzle: LDS chunk (r,c) holds global
// chunk (r, c^(r&7)). Readers hit all 32 banks (R6 measured: 0 conflicts).
__device__ inline void stage_sw(__bf16* S, const __bf16* G, int row0, int K, int k0,
                                int tid, int nchunks) {
#pragma unroll
    for (int ci = tid; ci < nchunks; ci += 256) {
        const int r  = ci >> 3;
        const int c  = ci & 7;
        const int cg = c ^ (r & 7);
        const char* g = (const char*)G + ((size_t)(row0 + r) * K + k0 + cg * 8) * 2;
        async16(g, (char*)S + ci * 16);
    }
}

// Swizzled fragment read: global chunk (r, cfrag) lives at LDS chunk cfrag^(r&7).
__device__ inline bf16x8 frag_sw(const __bf16* S, int r, int cfrag) {
    const int c = cfrag ^ (r & 7);
    return *(const bf16x8*)(S + r * 64 + c * 8);
}

// fp32 -> bf16 cast (vectorized). blockIdx.y selects {x, w_qkv, w_out}.
__global__ __launch_bounds__(256) void cast_mat(
    const float* __restrict__ s0, __bf16* __restrict__ h0, int n0,
    const float* __restrict__ s1, __bf16* __restrict__ h1, int n1,
    const float* __restrict__ s2, __bf16* __restrict__ h2, int n2)
{
    const float* s; __bf16* h; int n;
    if (blockIdx.y == 0)      { s = s0; h = h0; n = n0; }
    else if (blockIdx.y == 1) { s = s1; h = h1; n = n1; }
    else                      { s = s2; h = h2; n = n2; }
    const int base = (blockIdx.x * 256 + threadIdx.x) * 8;
    if (base >= n) return;
    float4 a = ((const float4*)(s + base))[0];
    float4 b = ((const float4*)(s + base))[1];
    float buf[8] = {a.x, a.y, a.z, a.w, b.x, b.y, b.z, b.w};
    bf16x8 hv;
#pragma unroll
    for (int j = 0; j < 8; j++) hv[j] = (__bf16)buf[j];
    *(bf16x8*)(h + base) = hv;
}

// QKV projection: C = A*W^T + bias (plain bf16 MFMA, both tiles in LDS),
// fused QK-norm, scatter q/k/v bf16 into [B,H,N,64]. TN=128.
__global__ __launch_bounds__(256) void gemm_qkv(
    const __bf16* __restrict__ A, const __bf16* __restrict__ W,
    const float* __restrict__ bias,
    __bf16* __restrict__ q, __bf16* __restrict__ k, __bf16* __restrict__ v,
    int M, int N, int K)
{
    __shared__ __bf16 sA[TM * BK];
    __shared__ __bf16 sW[TM * BK];

    const int tid  = threadIdx.x;
    const int lane = tid & 63;
    const int wave = tid >> 6;
    const int bm = blockIdx.y * TM;
    const int bn = blockIdx.x * 128;
    const int wm = (wave >> 1) * 64;
    const int wn = (wave & 1) * 64;
    const int frow = lane & 15;

    f32x4 acc[4][4] = {};

    for (int k0 = 0; k0 < K; k0 += BK) {
        stage_sw(sA, A, bm, K, k0, tid, TM * 8);
        stage_sw(sW, W, bn, K, k0, tid, TM * 8);
        __syncthreads();

#pragma unroll
        for (int half = 0; half < 2; half++) {
            const int cf = half * 4 + (lane >> 4);
            bf16x8 aF[4], bF[4];
#pragma unroll
            for (int t = 0; t < 4; t++) {
                aF[t] = frag_sw(sA, wm + t * 16 + frow, cf);
                bF[t] = frag_sw(sW, wn + t * 16 + frow, cf);
            }
#pragma unroll
            for (int i = 0; i < 4; i++)
#pragma unroll
                for (int j = 0; j < 4; j++)
                    acc[i][j] = __builtin_amdgcn_mfma_f32_16x16x32_bf16(aF[i], bF[j], acc[i][j], 0, 0, 0);
        }
        __syncthreads();
    }

    // wave's 64-col window = exactly one (tensor t, head h)
    const int col0 = bn + wn;
    const int t  = col0 >> 10;            // 0=q 1=k 2=v
    const int h  = (col0 & 1023) >> 6;

    float bv[4];
#pragma unroll
    for (int j = 0; j < 4; j++) bv[j] = bias[col0 + j * 16 + (lane & 15)];

    // fused QK-norm: per output row, 1/(||row||+eps)
    float inv_n[4][4];
    if (t < 2) {
#pragma unroll
        for (int i = 0; i < 4; i++)
#pragma unroll
            for (int r = 0; r < 4; r++) {
                float ss = 0.f;
#pragma unroll
                for (int j = 0; j < 4; j++) {
                    float val = acc[i][j][r] + bv[j];
                    ss = fmaf(val, val, ss);
                }
                ss += __shfl_xor(ss, 1);
                ss += __shfl_xor(ss, 2);
                ss += __shfl_xor(ss, 4);
                ss += __shfl_xor(ss, 8);
                inv_n[i][r] = 1.0f / (sqrtf(ss) + 1e-6f);
            }
    }

    __bf16* dstbase = (t == 0) ? q : (t == 1) ? k : v;
#pragma unroll
    for (int i = 0; i < 4; i++) {
        const int gmBase = bm + wm + i * 16 + (lane >> 4) * 4;
#pragma unroll
        for (int j = 0; j < 4; j++) {
            const int dd = (wn & 63) + j * 16 + (lane & 15);
#pragma unroll
            for (int r = 0; r < 4; r++) {
                const int gm = gmBase + r;
                float val = acc[i][j][r] + bv[j];
                if (t < 2) val *= inv_n[i][r];
                const int b  = gm >> 11;
                const int ii = gm & 2047;
                const size_t dst = (((size_t)(b * 16 + h) * 2048) + ii) * 64 + dd;
                dstbase[dst] = (__bf16)val;
            }
        }
    }
}

// Out projection: C = A*W^T + bias, plain bf16 1-term, fp32 out.
// TM=128, TN=64 -> 512 blocks (2/CU). Wave owns 64x32.
__global__ __launch_bounds__(256) void gemm_out(
    const __bf16* __restrict__ A, const __bf16* __restrict__ W,
    const float* __restrict__ bias, float* __restrict__ C,
    int M, int N, int K)
{
    __shared__ __bf16 sA[TM * BK];
    __shared__ __bf16 sW[64 * BK];

    const int tid  = threadIdx.x;
    const int lane = tid & 63;
    const int wave = tid >> 6;
    const int bm = blockIdx.y * TM;
    const int bn = blockIdx.x * 64;
    const int wm = (wave >> 1) * 64;
    const int wn = (wave & 1) * 32;
    const int frow = lane & 15;

    f32x4 acc[4][2] = {};

    for (int k0 = 0; k0 < K; k0 += BK) {
        stage_sw(sA, A, bm, K, k0, tid, TM * 8);
        stage_sw(sW, W, bn, K, k0, tid, 64 * 8);
        __syncthreads();

#pragma unroll
        for (int half = 0; half < 2; half++) {
            const int cf = half * 4 + (lane >> 4);
            bf16x8 aF[4], bF[2];
#pragma unroll
            for (int t = 0; t < 4; t++)
                aF[t] = frag_sw(sA, wm + t * 16 + frow, cf);
#pragma unroll
            for (int t = 0; t < 2; t++)
                bF[t] = frag_sw(sW, wn + t * 16 + frow, cf);
#pragma unroll
            for (int i = 0; i < 4; i++)
#pragma unroll
                for (int j = 0; j < 2; j++)
                    acc[i][j] = __builtin_amdgcn_mfma_f32_16x16x32_bf16(aF[i], bF[j], acc[i][j], 0, 0, 0);
        }
        __syncthreads();
    }

#pragma unroll
    for (int i = 0; i < 4; i++) {
        const int gmBase = bm + wm + i * 16 + (lane >> 4) * 4;
#pragma unroll
        for (int j = 0; j < 2; j++) {
            const int gn = bn + wn + j * 16 + (lane & 15);
            const float bvj = bias[gn];
#pragma unroll
            for (int r = 0; r < 4; r++)
                C[(size_t)(gmBase + r) * N + gn] = acc[i][j][r] + bvj;
        }
    }
}

// Dilated attention: 8 rows per wave; lane group g=lane>>3 owns row i0+g,
// lane&7 owns 8 head-dims (bf16x8, 16B loads). q,k,v: [B,H,N,64] bf16.
__global__ __launch_bounds__(256) void attn_sparse(
    const __bf16* __restrict__ q, const __bf16* __restrict__ k,
    const __bf16* __restrict__ v, __bf16* __restrict__ ao /*[B,N,D] bf16*/)
{
    const int wid  = blockIdx.x * 4 + (threadIdx.x >> 6);
    const int lane = threadIdx.x & 63;
    const int g    = lane >> 3;
    const int ld   = (lane & 7) * 8;

    const int bh = wid >> 8;            // 256 wave-tasks per (b,h)
    const int i  = (wid & 255) * 8 + g; // this lane-group's row

    const __bf16* qb = q + (size_t)bh * 2048 * 64;
    const __bf16* kb = k + (size_t)bh * 2048 * 64;
    const __bf16* vb = v + (size_t)bh * 2048 * 64;

    bf16x8 qv = *(const bf16x8*)(qb + (size_t)i * 64 + ld);
    float qf[8];
#pragma unroll
    for (int d = 0; d < 8; d++) qf[d] = (float)qv[d];

    float s[17];
#pragma unroll
    for (int t = 0; t < 17; t++) {
        const int j = i + 2 * t - 16;
        const bool valid = (j >= 0) && (j < 2048);
        const int jc = valid ? j : i;
        bf16x8 kv = *(const bf16x8*)(kb + (size_t)jc * 64 + ld);
        float prod = 0.f;
#pragma unroll
        for (int d = 0; d < 8; d++) prod = fmaf(qf[d], (float)kv[d], prod);
        prod += __shfl_xor(prod, 1);
        prod += __shfl_xor(prod, 2);
        prod += __shfl_xor(prod, 4);
        s[t] = valid ? prod : -INFINITY;
    }

    float m = s[0];
#pragma unroll
    for (int t = 1; t < 17; t++) m = fmaxf(m, s[t]);
    float denom = 0.f, p[17];
#pragma unroll
    for (int t = 0; t < 17; t++) { p[t] = __expf(s[t] - m); denom += p[t]; }
    const float inv = 1.0f / denom;

    float a[8] = {};
#pragma unroll
    for (int t = 0; t < 17; t++) {
        const int j = i + 2 * t - 16;
        const int jc = (j >= 0 && j < 2048) ? j : i;   // p[t]==0 when invalid
        bf16x8 vv = *(const bf16x8*)(vb + (size_t)jc * 64 + ld);
#pragma unroll
        for (int d = 0; d < 8; d++) a[d] = fmaf(p[t], (float)vv[d], a[d]);
    }

    const int b = bh >> 4, h = bh & 15;
    bf16x8 o;
#pragma unroll
    for (int d = 0; d < 8; d++) o[d] = (__bf16)(a[d] * inv);
    *(bf16x8*)(ao + ((size_t)(b * 2048 + i)) * 1024 + h * 64 + ld) = o;
}

extern "C" void kernel_launch(void* const* d_in, const int* in_sizes, int n_in,
                              void* d_out, int out_size, void* d_ws, size_t ws_size,
                              hipStream_t stream)
{
    const float* x     = (const float*)d_in[0];  // [2,2048,1024]
    const float* w_qkv = (const float*)d_in[1];  // [3072,1024]
    const float* b_qkv = (const float*)d_in[2];  // [3072]
    const float* w_out = (const float*)d_in[3];  // [1024,1024]
    const float* b_out = (const float*)d_in[4];  // [1024]
    float* out = (float*)d_out;                  // [2,2048,1024]

    const int Dn = 1024;
    const int M  = 4096;
    const int nx = 4194304, nwq = 3145728, nwo = 1048576;

    char* p = (char*)d_ws;
    __bf16* q   = (__bf16*)p;  p += (size_t)nx * 2;   // [2,16,2048,64]
    __bf16* kk  = (__bf16*)p;  p += (size_t)nx * 2;
    __bf16* vv  = (__bf16*)p;  p += (size_t)nx * 2;
    __bf16* xh  = (__bf16*)p;  p += (size_t)nx * 2;   // aliased to ao after gemm_qkv
    __bf16* wqh = (__bf16*)p;  p += (size_t)nwq * 2;
    __bf16* woh = (__bf16*)p;  p += (size_t)nwo * 2;
    __bf16* ao  = xh;

    // 0) cast x, w_qkv, w_out to bf16
    {
        dim3 grid(nx / 8 / 256, 3);
        hipLaunchKernelGGL(cast_mat, grid, dim3(256), 0, stream,
                           x, xh, nx, w_qkv, wqh, nwq, w_out, woh, nwo);
    }
    // 1) qkv projection + fused qk-norm -> q,k,v bf16 head layout
    {
        dim3 grid(3 * Dn / 128, M / TM);
        hipLaunchKernelGGL(gemm_qkv, grid, dim3(256), 0, stream,
                           xh, wqh, b_qkv, q, kk, vv, M, 3 * Dn, Dn);
    }
    // 2) sparse dilated attention -> ao bf16 [B,N,D]
    hipLaunchKernelGGL(attn_sparse, dim3(65536 / 32), dim3(256), 0, stream,
                       q, kk, vv, ao);
    // 3) output projection (1-term) -> fp32 out
    {
        dim3 grid(Dn / 64, M / TM);
        hipLaunchKernelGGL(gemm_out, grid, dim3(256), 0, stream,
                           ao, woh, b_out, out, M, Dn, Dn);
    }
}